// Round 2
// baseline (1173.434 us; speedup 1.0000x reference)
//
#include <hip/hip_runtime.h>

#define T_STEPS 100
#define B_SZ    2048
#define IN_DIM  784
#define HID_DIM 100
#define OUT_DIM 10
#define BM      128

// ---------------- Phase A: cur[r][h] = sum_k x[r][k] * w1[h][k], fp64 accumulation (order-robust) ----------------
__global__ __launch_bounds__(256, 2)
void snn_gemm1(const float* __restrict__ x,   // [rows][784] (chunk-offset)
               const float* __restrict__ w1,  // [100][784]
               double* __restrict__ cur)      // [rows][100]
{
  const int tid  = threadIdx.x;
  const int lane = tid & 63;
  const int h0   = (tid >> 6) * 25;          // 4 h-groups of 25
  const long rowBase = (long)blockIdx.x * BM;

  __shared__ float4 xs[2][BM][4];            // 128 rows x 16 k, XOR-swizzled float4 cols
  __shared__ double wsh[2][HID_DIM][18];     // w1 pre-converted to double; pad 18 (16B-align, mild write conflict)

  const float* xrow  = x  + (rowBase + (tid & 127)) * (long)IN_DIM;
  const float* w1row = w1 + (long)(tid < HID_DIM ? tid : 0) * IN_DIM;

  float4 xr0, xr1, xr2, xr3, wr0, wr1, wr2, wr3;
  const int swz = (tid >> 1) & 3;            // row-r swizzle = (r>>1)&3; consistent for reader since 64|rows step

  double acc[2][25];
#pragma unroll
  for (int mi = 0; mi < 2; ++mi)
#pragma unroll
    for (int hi = 0; hi < 25; ++hi) acc[mi][hi] = 0.0;

  auto LOAD = [&](int kc) {
    if (tid < BM) {
      const float4* xp = reinterpret_cast<const float4*>(xrow + kc * 16);
      xr0 = xp[0]; xr1 = xp[1]; xr2 = xp[2]; xr3 = xp[3];
    }
    if (tid < HID_DIM) {
      const float4* wp = reinterpret_cast<const float4*>(w1row + kc * 16);
      wr0 = wp[0]; wr1 = wp[1]; wr2 = wp[2]; wr3 = wp[3];
    }
  };
  auto STORE = [&](int buf) {
    if (tid < BM) {
      xs[buf][tid][0 ^ swz] = xr0; xs[buf][tid][1 ^ swz] = xr1;
      xs[buf][tid][2 ^ swz] = xr2; xs[buf][tid][3 ^ swz] = xr3;
    }
    if (tid < HID_DIM) {
      double* wd = wsh[buf][tid];
      wd[0]  = (double)wr0.x; wd[1]  = (double)wr0.y; wd[2]  = (double)wr0.z; wd[3]  = (double)wr0.w;
      wd[4]  = (double)wr1.x; wd[5]  = (double)wr1.y; wd[6]  = (double)wr1.z; wd[7]  = (double)wr1.w;
      wd[8]  = (double)wr2.x; wd[9]  = (double)wr2.y; wd[10] = (double)wr2.z; wd[11] = (double)wr2.w;
      wd[12] = (double)wr3.x; wd[13] = (double)wr3.y; wd[14] = (double)wr3.z; wd[15] = (double)wr3.w;
    }
  };

  LOAD(0); STORE(0); LOAD(1);
  __syncthreads();

#pragma unroll 1
  for (int kc = 0; kc < 49; ++kc) {          // 49 * 16 = 784
    if (kc + 1 < 49) STORE((kc + 1) & 1);
    if (kc + 2 < 49) LOAD(kc + 2);
    const int buf = kc & 1;
#pragma unroll 1
    for (int c = 0; c < 4; ++c) {
      double dx[2][4];
#pragma unroll
      for (int mi = 0; mi < 2; ++mi) {
        const float4 xv = xs[buf][mi * 64 + lane][c ^ swz];
        dx[mi][0] = (double)xv.x; dx[mi][1] = (double)xv.y;
        dx[mi][2] = (double)xv.z; dx[mi][3] = (double)xv.w;
      }
#pragma unroll
      for (int hi = 0; hi < 25; ++hi) {
        const double* wd = &wsh[buf][h0 + hi][c * 4];   // wave-uniform -> LDS broadcast
        const double w0 = wd[0], w1v = wd[1], w2v = wd[2], w3v = wd[3];
#pragma unroll
        for (int mi = 0; mi < 2; ++mi) {
          acc[mi][hi] = fma(dx[mi][0], w0,  acc[mi][hi]);
          acc[mi][hi] = fma(dx[mi][1], w1v, acc[mi][hi]);
          acc[mi][hi] = fma(dx[mi][2], w2v, acc[mi][hi]);
          acc[mi][hi] = fma(dx[mi][3], w3v, acc[mi][hi]);
        }
      }
    }
    __syncthreads();
  }

#pragma unroll
  for (int mi = 0; mi < 2; ++mi) {
    double* cp = cur + (rowBase + mi * 64 + lane) * HID_DIM + h0;
#pragma unroll
    for (int hi = 0; hi < 25; ++hi) cp[hi] = acc[mi][hi];
  }
}

// ---------------- Phase B: serial-in-time recursion, fp64 state ----------------
__global__ __launch_bounds__(256)
void snn_recur(const double* __restrict__ cur,  // [chunkT][2048][100]
               const float* __restrict__ w2,    // [10][100]
               double* __restrict__ mem1s, float* __restrict__ spk1s,
               double* __restrict__ mem2s, float* __restrict__ spk2s,
               float* __restrict__ outs,
               float* __restrict__ dout,
               int chunkT, int isFirst, int isLast)
{
  const int tid = threadIdx.x;
  const int b0  = blockIdx.x * 8;              // 8 samples per block
  __shared__ float w2l[OUT_DIM * HID_DIM];     // 1000
  __shared__ float spkl[8 * HID_DIM];          // 800

  if (tid < 250)
    reinterpret_cast<float4*>(w2l)[tid] = reinterpret_cast<const float4*>(w2)[tid];

  const bool pa = tid < 200;                   // 8*100/4 hidden units each
  const long aOff = (long)b0 * HID_DIM + tid * 4;
  double m1[4] = {0.0, 0.0, 0.0, 0.0};
  float4 s1 = make_float4(0.f, 0.f, 0.f, 0.f);
  if (pa && !isFirst) {
    const double2* mp = reinterpret_cast<const double2*>(mem1s + aOff);
    double2 a = mp[0], b = mp[1];
    m1[0] = a.x; m1[1] = a.y; m1[2] = b.x; m1[3] = b.y;
    s1 = *reinterpret_cast<const float4*>(spk1s + aOff);
  }

  const bool pb = tid < 80;                    // 8 samples * 10 outputs
  const int  ss = tid / 10, oo = tid % 10;
  const long bOff = (long)b0 * OUT_DIM + tid;
  double m2 = 0.0;
  float s2 = 0.f, oacc = 0.f;
  if (pb && !isFirst) { m2 = mem2s[bOff]; s2 = spk2s[bOff]; oacc = outs[bOff]; }

  __syncthreads();

  for (int tt = 0; tt < chunkT; ++tt) {
    if (pa) {
      const double2* cp = reinterpret_cast<const double2*>(
          cur + ((long)tt * B_SZ + b0) * HID_DIM + tid * 4);
      const double2 ca = cp[0], cb = cp[1];
      double cu[4] = {ca.x, ca.y, cb.x, cb.y};
      float4 sp;
      float* spv = &sp.x;
      const float* s1v = &s1.x;
#pragma unroll
      for (int j = 0; j < 4; ++j) {
        double m = 0.9 * m1[j];
        m = m + cu[j];
        m = m - (double)s1v[j];
        spv[j] = (m > 1.0) ? 1.0f : 0.0f;
        m1[j] = m;
      }
      s1 = sp;
      *reinterpret_cast<float4*>(&spkl[tid * 4]) = sp;
    }
    __syncthreads();
    if (pb) {
      const float* sr = &spkl[ss * HID_DIM];
      const float* wr = &w2l[oo * HID_DIM];
      double a0 = 0.0, a1 = 0.0, a2 = 0.0, a3 = 0.0;
#pragma unroll
      for (int h = 0; h < 100; h += 4) {       // order-free in fp64; 4 chains for latency
        a0 = fma((double)sr[h],     (double)wr[h],     a0);
        a1 = fma((double)sr[h + 1], (double)wr[h + 1], a1);
        a2 = fma((double)sr[h + 2], (double)wr[h + 2], a2);
        a3 = fma((double)sr[h + 3], (double)wr[h + 3], a3);
      }
      const double a = (a0 + a1) + (a2 + a3);
      double m = 0.9 * m2;
      m = m + a;
      m = m - (double)s2;
      const float sp = (m > 1.0) ? 1.0f : 0.0f;
      m2 = m; s2 = sp; oacc += sp;
    }
    __syncthreads();
  }

  if (pa) {
    double2* mp = reinterpret_cast<double2*>(mem1s + aOff);
    mp[0] = make_double2(m1[0], m1[1]);
    mp[1] = make_double2(m1[2], m1[3]);
    *reinterpret_cast<float4*>(spk1s + aOff) = s1;
  }
  if (pb) {
    mem2s[bOff] = m2; spk2s[bOff] = s2; outs[bOff] = oacc;
    if (isLast) dout[bOff] = oacc;
  }
}

// ---------------- host ----------------
extern "C" void kernel_launch(void* const* d_in, const int* in_sizes, int n_in,
                              void* d_out, int out_size, void* d_ws, size_t ws_size,
                              hipStream_t stream) {
  const float* x  = (const float*)d_in[0];   // [100,2048,784]
  const float* w1 = (const float*)d_in[1];   // [100,784]
  const float* w2 = (const float*)d_in[2];   // [10,100]
  float* out = (float*)d_out;

  char* ws = (char*)d_ws;
  // bytes: mem1(d) 1,638,400 | spk1(f) 819,200 | mem2(d) 163,840 | spk2(f) 81,920 | outacc(f) 81,920 | cur(d)...
  double* mem1s = (double*)(ws);
  float*  spk1s = (float*) (ws + 1638400);
  double* mem2s = (double*)(ws + 2457600);
  float*  spk2s = (float*) (ws + 2621440);
  float*  outs  = (float*) (ws + 2703360);
  double* cur   = (double*)(ws + 2785280);

  const size_t perT = (size_t)B_SZ * HID_DIM * 8;  // 1,638,400 B per timestep of cur (double)
  size_t curCap = ws_size > (size_t)2785280 ? ws_size - 2785280 : 0;
  int Tc = (int)(curCap / perT);
  if (Tc > T_STEPS) Tc = T_STEPS;
  if (Tc < 1) Tc = 1;

  for (int t0 = 0; t0 < T_STEPS; t0 += Tc) {
    const int ct = (T_STEPS - t0 < Tc) ? (T_STEPS - t0) : Tc;
    snn_gemm1<<<dim3(ct * (B_SZ / BM)), dim3(256), 0, stream>>>(
        x + (size_t)t0 * B_SZ * IN_DIM, w1, cur);
    snn_recur<<<dim3(B_SZ / 8), dim3(256), 0, stream>>>(
        cur, w2, mem1s, spk1s, mem2s, spk2s, outs, out,
        ct, (t0 == 0) ? 1 : 0, (t0 + ct >= T_STEPS) ? 1 : 0);
  }
}